// Round 11
// baseline (1367.660 us; speedup 1.0000x reference)
//
#include <hip/hip_runtime.h>

#define N_NODES 50000
#define N_EDGES 1600000
#define HDIM 128
#define N_CLASSES 40
#define N_LAYERS 8
#define CAP 128                 // max stored in-degree; Poisson(32): P(>128) ~ 1e-19/node

#define BUILD_BLOCKS 782        // ceil(1.6M/8/256)
#define PREP_BLOCKS  600        // wt 576 + wot 24
#define GEMM0_BLOCKS 782        // ceil(50000/64)
#define WT_OFF 16384            // LDS: A-tile 16K | Wt 32K

typedef _Float16 f16;
typedef _Float16 f16x2 __attribute__((ext_vector_type(2)));
typedef _Float16 f16x4 __attribute__((ext_vector_type(4)));
typedef _Float16 f16x8 __attribute__((ext_vector_type(8)));
typedef float f32x4 __attribute__((ext_vector_type(4)));
typedef int i32x4 __attribute__((ext_vector_type(4)));

__device__ __forceinline__ int clamp_idx(int v) {
    v = v < 0 ? 0 : v;
    return v >= N_NODES ? N_NODES - 1 : v;
}

// ---------------- fused setup: CSR build || weight prep || gemm0 (x@W_in -> h0) ----------------
// Build blocks stall ~150us on fabric atomics; prep+gemm0 blocks flow through
// freed CU slots and hide completely under the atomic drain.

__global__ __launch_bounds__(256) void setup_kernel(
        const int* __restrict__ ei, const float* __restrict__ x,
        const float* __restrict__ W_in, const float* __restrict__ b_in,
        const float* __restrict__ gcn_W, const float* __restrict__ W_out,
        int* __restrict__ deg_cnt, int* __restrict__ col_cnt,
        unsigned short* __restrict__ e_slot,
        f16* __restrict__ wt, f16* __restrict__ wot, f16* __restrict__ h0_out) {
    __shared__ uint4 smem4[3072];                // 48 KiB (gemm0 role only)
    char* smem = (char*)smem4;
    int b = blockIdx.x;
    int tid = threadIdx.x;

    if (b < BUILD_BLOCKS) {
        int t = b * 256 + tid;                   // 8 edges per thread
        if (t < N_EDGES / 8) {
            i32x4 ra = ((const i32x4*)ei)[2 * t];
            i32x4 rb = ((const i32x4*)ei)[2 * t + 1];
            i32x4 ca = ((const i32x4*)(ei + N_EDGES))[2 * t];
            i32x4 cb = ((const i32x4*)(ei + N_EDGES))[2 * t + 1];
            int rs[8] = {ra[0], ra[1], ra[2], ra[3], rb[0], rb[1], rb[2], rb[3]};
            int cs[8] = {ca[0], ca[1], ca[2], ca[3], cb[0], cb[1], cb[2], cb[3]};
#pragma unroll
            for (int i = 0; i < 8; ++i) {
                int r = clamp_idx(rs[i]);
                int c = clamp_idx(cs[i]);
                if (r != c) {
                    atomicAdd(&deg_cnt[r], 1);               // fire-and-forget
                    int s = atomicAdd(&col_cnt[c], 1);       // slot
                    if (s < CAP) e_slot[(size_t)c * CAP + s] = (unsigned short)r;
                }
            }
        }
        return;
    }
    if (b < BUILD_BLOCKS + PREP_BLOCKS) {
        int idx = (b - BUILD_BLOCKS) * 256 + tid;
        if (idx < 9 * HDIM * HDIM) {
            // W_in + gcn_W -> fp16, transposed: wt[mat][n][k]  (mat 0 unused now)
            int mat = idx >> 14;
            int rem = idx & 16383;
            int k = rem >> 7, n = rem & 127;
            float v = (mat == 0) ? W_in[rem] : gcn_W[(mat - 1) * 16384 + rem];
            wt[mat * 16384 + n * 128 + k] = (f16)v;
        } else {
            int j = idx - 9 * HDIM * HDIM;                   // 0..6143
            if (j < 48 * 128) {
                int n = j >> 7, k = j & 127;                 // wot[n][k], pad n>=40
                wot[n * 128 + k] = (n < N_CLASSES) ? (f16)W_out[k * N_CLASSES + n] : (f16)0.f;
            }
        }
        return;
    }

    // ---- gemm0 role: h0 = relu(x @ W_in + b_in), f32 inputs converted in staging ----
    int r0 = (b - BUILD_BLOCKS - PREP_BLOCKS) * 64;

    // A-tile: 64 rows x 128 f32 -> f16, swizzled (16B-chunk XOR by row&7)
    const float4* x4 = (const float4*)x;
    for (int c = tid; c < 2048; c += 256) {
        int row = c >> 5, f4 = c & 31;
        int grow = r0 + row; if (grow >= N_NODES) grow = N_NODES - 1;
        float4 v = x4[(size_t)grow * 32 + f4];
        f16x4 h; h[0] = (f16)v.x; h[1] = (f16)v.y; h[2] = (f16)v.z; h[3] = (f16)v.w;
        int addr = row * 256 + ((((f4 >> 1) << 4) ^ ((row & 7) << 4)) + (f4 & 1) * 8);
        *(f16x4*)&smem[addr] = h;
    }
    // Wt-tile: W_in[k][n] -> LDS Wt[n][k] f16 (coalesced reads; scattered 2B ds writes, hidden)
    for (int idx = tid; idx < 16384; idx += 256) {
        int k = idx >> 7, n = idx & 127;
        float v = W_in[k * 128 + n];
        int addr = WT_OFF + n * 256 + ((((k >> 3) << 4) ^ ((n & 7) << 4)) + (k & 7) * 2);
        *(f16*)&smem[addr] = (f16)v;
    }
    __syncthreads();

    int l = tid & 63, w = tid >> 6;
    int wr = w >> 1, wc = w & 1;
    int lg = l >> 4, lm = l & 15;
    union F8 { f16x8 v8; struct { f16x4 lo, hi; } p; };
    f32x4 acc[2][4];
#pragma unroll
    for (int m = 0; m < 2; ++m)
#pragma unroll
        for (int j = 0; j < 4; ++j) acc[m][j] = (f32x4){0.f, 0.f, 0.f, 0.f};
#pragma unroll
    for (int kk = 0; kk < 4; ++kk) {
        int boff = kk * 64 + lg * 8;
        F8 a[2], bb[4];
#pragma unroll
        for (int m = 0; m < 2; ++m) {
            int row = wr * 32 + m * 16 + lm;
            int swz = (row & 7) << 4;
            int rb = row * 256;
            a[m].p.lo = *(const f16x4*)&smem[rb + (boff ^ swz)];
            a[m].p.hi = *(const f16x4*)&smem[rb + ((boff + 32) ^ swz)];
        }
#pragma unroll
        for (int j = 0; j < 4; ++j) {
            int n = wc * 64 + j * 16 + lm;
            int swz = (n & 7) << 4;
            int nb = WT_OFF + n * 256;
            bb[j].p.lo = *(const f16x4*)&smem[nb + (boff ^ swz)];
            bb[j].p.hi = *(const f16x4*)&smem[nb + ((boff + 32) ^ swz)];
        }
#pragma unroll
        for (int m = 0; m < 2; ++m)
#pragma unroll
            for (int j = 0; j < 4; ++j)
                acc[m][j] = __builtin_amdgcn_mfma_f32_16x16x32_f16(a[m].v8, bb[j].v8, acc[m][j], 0, 0, 0);
    }
#pragma unroll
    for (int m = 0; m < 2; ++m) {
#pragma unroll
        for (int r = 0; r < 4; ++r) {
            int row = r0 + wr * 32 + m * 16 + lg * 4 + r;
            if (row < N_NODES) {
#pragma unroll
                for (int j = 0; j < 4; ++j) {
                    int col = wc * 64 + j * 16 + lm;
                    float v = fmaxf(acc[m][j][r] + b_in[col], 0.f);
                    h0_out[(size_t)row * HDIM + col] = (f16)v;
                }
            }
        }
    }
}

// combo + hs0 = dis*h0 (one wave per node)
__global__ __launch_bounds__(256) void combo_scale(
        const int* __restrict__ deg_cnt, const f16* __restrict__ h0,
        float4* __restrict__ combo, f16* __restrict__ hs0) {
    int node = blockIdx.x * 4 + (threadIdx.x >> 6);
    int lane = threadIdx.x & 63;
    if (node >= N_NODES) return;
    float d = (float)(deg_cnt[node] + 1);
    float dis = rsqrtf(d);
    float g = sqrtf(d);
    if (lane == 0) combo[node] = make_float4(dis, 0.8f * dis, (0.8f / d + 0.1f) * g, g);
    f16x2 h = ((const f16x2*)h0)[(size_t)node * 64 + lane];
    f16x2 o; o[0] = (f16)(dis * (float)h[0]); o[1] = (f16)(dis * (float)h[1]);
    ((f16x2*)hs0)[(size_t)node * 64 + lane] = o;
}

// ---------------- fused layer: aggregate 64 nodes -> LDS A-tile -> MFMA -> hs_out ----------------
// 4 waves; wave aggregates 16 nodes (lane owns f16x2 of the 256B row, 8 gathers
// in flight), writes combined p-row into the swizzled A-tile, then the standard
// MFMA phase. Wt staging issued before gathers so it lands for free.

__global__ __launch_bounds__(256, 3) void layer_fused(
        const f16* __restrict__ hs, const f16* __restrict__ h0_16,
        const int* __restrict__ col_cnt, const unsigned short* __restrict__ e_slot,
        const float4* __restrict__ combo, const f16* __restrict__ Wt,
        const float* __restrict__ sb, f16* __restrict__ hs_out) {
    __shared__ uint4 smem4[3072];                // 48 KiB: A 16K | Wt 32K
    char* smem = (char*)smem4;
    int tid = threadIdx.x;
    int lane = tid & 63, w4 = tid >> 6;
    int r0 = blockIdx.x * 64;

    // stage Wt early (overlaps the gather phase via vmcnt)
    const uint4* Wsrc = (const uint4*)Wt;
    for (int c = tid; c < 2048; c += 256) {
        int n = c >> 4, q = c & 15;
        uint4 v = Wsrc[n * 16 + q];
        *(uint4*)&smem[WT_OFF + n * 256 + ((q * 16) ^ ((n & 7) << 4))] = v;
    }

    // aggregation: wave w4 handles tile rows w4*16 .. w4*16+15
    const f16x2* hp = (const f16x2*)hs;
    int chunk = (lane >> 2) << 4;                // 16B chunk base within row
    int sub = (lane & 3) << 2;                   // byte offset within chunk
    for (int t = 0; t < 16; ++t) {
        int row = w4 * 16 + t;
        int node = r0 + row;
        float px = 0.f, py = 0.f;
        if (node < N_NODES) {
            int cnt = col_cnt[node]; if (cnt > CAP) cnt = CAP;
            const unsigned short* slots = e_slot + (size_t)node * CAP;
            float ax = 0.f, ay = 0.f;
            int e = 0;
            for (; e + 8 <= cnt; e += 8) {
                ushort4 sa = *(const ushort4*)(slots + e);
                ushort4 sbv = *(const ushort4*)(slots + e + 4);
                f16x2 v0 = hp[(size_t)sa.x * 64 + lane];
                f16x2 v1 = hp[(size_t)sa.y * 64 + lane];
                f16x2 v2 = hp[(size_t)sa.z * 64 + lane];
                f16x2 v3 = hp[(size_t)sa.w * 64 + lane];
                f16x2 v4 = hp[(size_t)sbv.x * 64 + lane];
                f16x2 v5 = hp[(size_t)sbv.y * 64 + lane];
                f16x2 v6 = hp[(size_t)sbv.z * 64 + lane];
                f16x2 v7 = hp[(size_t)sbv.w * 64 + lane];
                ax += (float)v0[0] + (float)v1[0] + (float)v2[0] + (float)v3[0]
                    + (float)v4[0] + (float)v5[0] + (float)v6[0] + (float)v7[0];
                ay += (float)v0[1] + (float)v1[1] + (float)v2[1] + (float)v3[1]
                    + (float)v4[1] + (float)v5[1] + (float)v6[1] + (float)v7[1];
            }
            for (; e + 4 <= cnt; e += 4) {
                ushort4 s4 = *(const ushort4*)(slots + e);
                f16x2 v0 = hp[(size_t)s4.x * 64 + lane];
                f16x2 v1 = hp[(size_t)s4.y * 64 + lane];
                f16x2 v2 = hp[(size_t)s4.z * 64 + lane];
                f16x2 v3 = hp[(size_t)s4.w * 64 + lane];
                ax += (float)v0[0] + (float)v1[0] + (float)v2[0] + (float)v3[0];
                ay += (float)v0[1] + (float)v1[1] + (float)v2[1] + (float)v3[1];
            }
            for (; e < cnt; ++e) {
                int r = slots[e];
                f16x2 v = hp[(size_t)r * 64 + lane];
                ax += (float)v[0];
                ay += (float)v[1];
            }
            float4 cb = combo[node];
            f16x2 hw = hp[(size_t)node * 64 + lane];
            f16x2 h0v = ((const f16x2*)h0_16)[(size_t)node * 64 + lane];
            px = cb.y * ax + cb.z * (float)hw[0] + 0.1f * (float)h0v[0];
            py = cb.y * ay + cb.z * (float)hw[1] + 0.1f * (float)h0v[1];
        }
        f16x2 o; o[0] = (f16)px; o[1] = (f16)py;
        *(f16x2*)&smem[row * 256 + (chunk ^ ((row & 7) << 4)) + sub] = o;
    }
    __syncthreads();

    // MFMA phase (identical to gemm_mfma, mode 1) + epilogue hs = dis*max(v, sb)
    int wr = w4 >> 1, wc = w4 & 1;
    int lg = lane >> 4, lm = lane & 15;
    union F8 { f16x8 v8; struct { f16x4 lo, hi; } p; };
    f32x4 acc[2][4];
#pragma unroll
    for (int m = 0; m < 2; ++m)
#pragma unroll
        for (int j = 0; j < 4; ++j) acc[m][j] = (f32x4){0.f, 0.f, 0.f, 0.f};
#pragma unroll
    for (int kk = 0; kk < 4; ++kk) {
        int boff = kk * 64 + lg * 8;
        F8 a[2], bb[4];
#pragma unroll
        for (int m = 0; m < 2; ++m) {
            int row = wr * 32 + m * 16 + lm;
            int swz = (row & 7) << 4;
            int rb = row * 256;
            a[m].p.lo = *(const f16x4*)&smem[rb + (boff ^ swz)];
            a[m].p.hi = *(const f16x4*)&smem[rb + ((boff + 32) ^ swz)];
        }
#pragma unroll
        for (int j = 0; j < 4; ++j) {
            int n = wc * 64 + j * 16 + lm;
            int swz = (n & 7) << 4;
            int nb = WT_OFF + n * 256;
            bb[j].p.lo = *(const f16x4*)&smem[nb + (boff ^ swz)];
            bb[j].p.hi = *(const f16x4*)&smem[nb + ((boff + 32) ^ swz)];
        }
#pragma unroll
        for (int m = 0; m < 2; ++m)
#pragma unroll
            for (int j = 0; j < 4; ++j)
                acc[m][j] = __builtin_amdgcn_mfma_f32_16x16x32_f16(a[m].v8, bb[j].v8, acc[m][j], 0, 0, 0);
    }
#pragma unroll
    for (int m = 0; m < 2; ++m) {
#pragma unroll
        for (int r = 0; r < 4; ++r) {
            int row = r0 + wr * 32 + m * 16 + lg * 4 + r;
            if (row < N_NODES) {
                float dis = combo[row].x;
#pragma unroll
                for (int j = 0; j < 4; ++j) {
                    int col = wc * 64 + j * 16 + lm;
                    float v = fmaxf(acc[m][j][r], sb[col]);
                    hs_out[(size_t)row * HDIM + col] = (f16)(dis * v);
                }
            }
        }
    }
}

// ---------------- output layer via MFMA: out = (hs/dis) @ W_out + b_out ----------------
#define WOT_OFF 16384

__global__ __launch_bounds__(256) void out_mfma(
        const f16* __restrict__ A, const f16* __restrict__ Wot,
        const float* __restrict__ bo, const float4* __restrict__ combo,
        float* __restrict__ out) {
    __shared__ uint4 smem4[1792];                // 28 KiB: A 16K | Wot 12K
    char* smem = (char*)smem4;
    int tid = threadIdx.x;
    int r0 = blockIdx.x * 64;

    const uint4* Asrc = (const uint4*)A;
    for (int c = tid; c < 1024; c += 256) {
        int row = c >> 4, q = c & 15;
        int grow = r0 + row; if (grow >= N_NODES) grow = N_NODES - 1;
        uint4 v = Asrc[(size_t)grow * 16 + q];
        *(uint4*)&smem[row * 256 + ((q * 16) ^ ((row & 7) << 4))] = v;
    }
    const uint4* Wsrc = (const uint4*)Wot;
    for (int c = tid; c < 768; c += 256) {
        int n = c >> 4, q = c & 15;
        uint4 v = Wsrc[n * 16 + q];
        *(uint4*)&smem[WOT_OFF + n * 256 + ((q * 16) ^ ((n & 7) << 4))] = v;
    }
    __syncthreads();

    int l = tid & 63, w = tid >> 6;
    int lg = l >> 4, lm = l & 15;

    union F8 { f16x8 v8; struct { f16x4 lo, hi; } p; };
    f32x4 acc[3];
#pragma unroll
    for (int j = 0; j < 3; ++j) acc[j] = (f32x4){0.f, 0.f, 0.f, 0.f};

#pragma unroll
    for (int kk = 0; kk < 4; ++kk) {
        int boff = kk * 64 + lg * 8;
        F8 a, b[3];
        int row = w * 16 + lm;
        int swz = (row & 7) << 4;
        int rb = row * 256;
        a.p.lo = *(const f16x4*)&smem[rb + (boff ^ swz)];
        a.p.hi = *(const f16x4*)&smem[rb + ((boff + 32) ^ swz)];
#pragma unroll
        for (int j = 0; j < 3; ++j) {
            int n = j * 16 + lm;
            int swz2 = (n & 7) << 4;
            int nb = WOT_OFF + n * 256;
            b[j].p.lo = *(const f16x4*)&smem[nb + (boff ^ swz2)];
            b[j].p.hi = *(const f16x4*)&smem[nb + ((boff + 32) ^ swz2)];
        }
#pragma unroll
        for (int j = 0; j < 3; ++j)
            acc[j] = __builtin_amdgcn_mfma_f32_16x16x32_f16(a.v8, b[j].v8, acc[j], 0, 0, 0);
    }

#pragma unroll
    for (int r = 0; r < 4; ++r) {
        int row = r0 + w * 16 + lg * 4 + r;
        if (row < N_NODES) {
            float g2 = combo[row].w;      // 1/dis: un-scale the hs row
#pragma unroll
            for (int j = 0; j < 3; ++j) {
                int col = j * 16 + lm;
                if (col < N_CLASSES)
                    out[(size_t)row * N_CLASSES + col] = g2 * acc[j][r] + bo[col];
            }
        }
    }
}

// ---------------- launch ----------------

extern "C" void kernel_launch(void* const* d_in, const int* in_sizes, int n_in,
                              void* d_out, int out_size, void* d_ws, size_t ws_size,
                              hipStream_t stream) {
    const float* x       = (const float*)d_in[0];
    const int*   ei      = (const int*)d_in[1];
    const float* W_in    = (const float*)d_in[2];
    const float* b_in    = (const float*)d_in[3];
    const float* gcn_W   = (const float*)d_in[4];
    const float* srelu_b = (const float*)d_in[5];
    const float* W_out   = (const float*)d_in[6];
    const float* b_out   = (const float*)d_in[7];
    float* outp = (float*)d_out;

    char* ws = (char*)d_ws;
    size_t off = 0;
    auto alloc = [&](size_t bytes) -> void* {
        void* p = ws + off;
        off += (bytes + 255) & ~(size_t)255;
        return p;
    };
    int*    deg_cnt = (int*)alloc((size_t)N_NODES * 4);
    int*    col_cnt = (int*)alloc((size_t)N_NODES * 4);
    float4* combo   = (float4*)alloc((size_t)N_NODES * 16);
    unsigned short* e_slot = (unsigned short*)alloc((size_t)N_NODES * CAP * 2);
    f16*    wt16    = (f16*)alloc((size_t)9 * HDIM * HDIM * 2);
    f16*    wot16   = (f16*)alloc((size_t)48 * HDIM * 2);
    f16*    h0_16   = (f16*)alloc((size_t)N_NODES * HDIM * 2);
    f16*    hs0     = (f16*)alloc((size_t)N_NODES * HDIM * 2);
    f16*    hsA     = (f16*)alloc((size_t)N_NODES * HDIM * 2);
    f16*    hsB     = (f16*)alloc((size_t)N_NODES * HDIM * 2);

    hipMemsetAsync(deg_cnt, 0, (size_t)N_NODES * 4, stream);
    hipMemsetAsync(col_cnt, 0, (size_t)N_NODES * 4, stream);

    setup_kernel<<<BUILD_BLOCKS + PREP_BLOCKS + GEMM0_BLOCKS, 256, 0, stream>>>(
        ei, x, W_in, b_in, gcn_W, W_out, deg_cnt, col_cnt, e_slot, wt16, wot16, h0_16);
    combo_scale<<<(N_NODES + 3) / 4, 256, 0, stream>>>(deg_cnt, h0_16, combo, hs0);

    const f16* hcur = hs0;
    for (int l = 0; l < N_LAYERS; ++l) {
        f16* hnext = (l & 1) ? hsB : hsA;
        layer_fused<<<(N_NODES + 63) / 64, 256, 0, stream>>>(
            hcur, h0_16, col_cnt, e_slot, combo,
            wt16 + (size_t)(l + 1) * HDIM * HDIM, srelu_b + (size_t)l * HDIM, hnext);
        hcur = hnext;
    }

    out_mfma<<<(N_NODES + 63) / 64, 256, 0, stream>>>(hcur, wot16, b_out, combo, outp);
}

// Round 12
// 690.473 us; speedup vs baseline: 1.9808x; 1.9808x over previous
//
#include <hip/hip_runtime.h>

#define N_NODES 50000
#define N_EDGES 1600000
#define HDIM 128
#define N_CLASSES 40
#define N_LAYERS 8
#define CAP 128                 // max stored in-degree; Poisson(32): P(>128) ~ 1e-19/node

#define BUILD_BLOCKS 782        // ceil(1.6M/8/256)
#define GEMM0_BLOCKS 782        // ceil(50000/64)
#define PREP_BLOCKS  600        // wt 576 + wot 24
#define WT_OFF 16384            // LDS: A-tile 16K | Wt 32K

typedef _Float16 f16;
typedef _Float16 f16x2 __attribute__((ext_vector_type(2)));
typedef _Float16 f16x4 __attribute__((ext_vector_type(4)));
typedef _Float16 f16x8 __attribute__((ext_vector_type(8)));
typedef float f32x4 __attribute__((ext_vector_type(4)));
typedef int i32x4 __attribute__((ext_vector_type(4)));

__device__ __forceinline__ int clamp_idx(int v) {
    v = v < 0 ? 0 : v;
    return v >= N_NODES ? N_NODES - 1 : v;
}

// ---------------- fused setup: CSR build || gemm0, INTERLEAVED block roles ----------------
// Even blocks [0,1564): build (fabric-atomic-bound, needs no occupancy).
// Odd blocks: gemm0 = relu(x @ W_in + b_in) -> h0 (f32 inputs converted in staging).
// Interleaving puts a mix of roles on every CU so gemm0 streams under the
// atomic drain (round-11 lesson: concatenated ranges serialize at 3 blocks/CU).

__global__ __launch_bounds__(256) void setup_kernel(
        const int* __restrict__ ei, const float* __restrict__ x,
        const float* __restrict__ W_in, const float* __restrict__ b_in,
        const float* __restrict__ gcn_W, const float* __restrict__ W_out,
        int* __restrict__ deg_cnt, int* __restrict__ col_cnt,
        unsigned short* __restrict__ e_slot,
        f16* __restrict__ wt, f16* __restrict__ wot, f16* __restrict__ h0_out) {
    __shared__ uint4 smem4[3072];                // 48 KiB (gemm0 role only)
    char* smem = (char*)smem4;
    int b = blockIdx.x;
    int tid = threadIdx.x;

    if (b < BUILD_BLOCKS + GEMM0_BLOCKS && (b & 1) == 0) {
        // ---- build role ----
        int t = (b >> 1) * 256 + tid;            // 8 edges per thread
        if (t < N_EDGES / 8) {
            i32x4 ra = ((const i32x4*)ei)[2 * t];
            i32x4 rb = ((const i32x4*)ei)[2 * t + 1];
            i32x4 ca = ((const i32x4*)(ei + N_EDGES))[2 * t];
            i32x4 cb = ((const i32x4*)(ei + N_EDGES))[2 * t + 1];
            int rs[8] = {ra[0], ra[1], ra[2], ra[3], rb[0], rb[1], rb[2], rb[3]};
            int cs[8] = {ca[0], ca[1], ca[2], ca[3], cb[0], cb[1], cb[2], cb[3]};
#pragma unroll
            for (int i = 0; i < 8; ++i) {
                int r = clamp_idx(rs[i]);
                int c = clamp_idx(cs[i]);
                if (r != c) {
                    atomicAdd(&deg_cnt[r], 1);               // fire-and-forget
                    int s = atomicAdd(&col_cnt[c], 1);       // returned: slot
                    if (s < CAP) e_slot[(size_t)c * CAP + s] = (unsigned short)r;
                }
            }
        }
        return;
    }
    if (b >= BUILD_BLOCKS + GEMM0_BLOCKS) {
        // ---- prep role (tail) ----
        int idx = (b - BUILD_BLOCKS - GEMM0_BLOCKS) * 256 + tid;
        if (idx < 9 * HDIM * HDIM) {
            int mat = idx >> 14;
            int rem = idx & 16383;
            int k = rem >> 7, n = rem & 127;
            float v = (mat == 0) ? W_in[rem] : gcn_W[(mat - 1) * 16384 + rem];
            wt[mat * 16384 + n * 128 + k] = (f16)v;
        } else {
            int j = idx - 9 * HDIM * HDIM;                   // 0..6143
            if (j < 48 * 128) {
                int n = j >> 7, k = j & 127;                 // wot[n][k], pad n>=40
                wot[n * 128 + k] = (n < N_CLASSES) ? (f16)W_out[k * N_CLASSES + n] : (f16)0.f;
            }
        }
        return;
    }

    // ---- gemm0 role (odd blocks): h0 = relu(x @ W_in + b_in) ----
    int r0 = (b >> 1) * 64;

    const float4* x4 = (const float4*)x;
    for (int c = tid; c < 2048; c += 256) {
        int row = c >> 5, f4 = c & 31;
        int grow = r0 + row; if (grow >= N_NODES) grow = N_NODES - 1;
        float4 v = x4[(size_t)grow * 32 + f4];
        f16x4 h; h[0] = (f16)v.x; h[1] = (f16)v.y; h[2] = (f16)v.z; h[3] = (f16)v.w;
        int addr = row * 256 + ((((f4 >> 1) << 4) ^ ((row & 7) << 4)) + (f4 & 1) * 8);
        *(f16x4*)&smem[addr] = h;
    }
    for (int idx = tid; idx < 16384; idx += 256) {
        int k = idx >> 7, n = idx & 127;
        float v = W_in[k * 128 + n];
        int addr = WT_OFF + n * 256 + ((((k >> 3) << 4) ^ ((n & 7) << 4)) + (k & 7) * 2);
        *(f16*)&smem[addr] = (f16)v;
    }
    __syncthreads();

    int l = tid & 63, w = tid >> 6;
    int wr = w >> 1, wc = w & 1;
    int lg = l >> 4, lm = l & 15;
    union F8 { f16x8 v8; struct { f16x4 lo, hi; } p; };
    f32x4 acc[2][4];
#pragma unroll
    for (int m = 0; m < 2; ++m)
#pragma unroll
        for (int j = 0; j < 4; ++j) acc[m][j] = (f32x4){0.f, 0.f, 0.f, 0.f};
#pragma unroll
    for (int kk = 0; kk < 4; ++kk) {
        int boff = kk * 64 + lg * 8;
        F8 a[2], bb[4];
#pragma unroll
        for (int m = 0; m < 2; ++m) {
            int row = wr * 32 + m * 16 + lm;
            int swz = (row & 7) << 4;
            int rb = row * 256;
            a[m].p.lo = *(const f16x4*)&smem[rb + (boff ^ swz)];
            a[m].p.hi = *(const f16x4*)&smem[rb + ((boff + 32) ^ swz)];
        }
#pragma unroll
        for (int j = 0; j < 4; ++j) {
            int n = wc * 64 + j * 16 + lm;
            int swz = (n & 7) << 4;
            int nb = WT_OFF + n * 256;
            bb[j].p.lo = *(const f16x4*)&smem[nb + (boff ^ swz)];
            bb[j].p.hi = *(const f16x4*)&smem[nb + ((boff + 32) ^ swz)];
        }
#pragma unroll
        for (int m = 0; m < 2; ++m)
#pragma unroll
            for (int j = 0; j < 4; ++j)
                acc[m][j] = __builtin_amdgcn_mfma_f32_16x16x32_f16(a[m].v8, bb[j].v8, acc[m][j], 0, 0, 0);
    }
#pragma unroll
    for (int m = 0; m < 2; ++m) {
#pragma unroll
        for (int r = 0; r < 4; ++r) {
            int row = r0 + wr * 32 + m * 16 + lg * 4 + r;
            if (row < N_NODES) {
#pragma unroll
                for (int j = 0; j < 4; ++j) {
                    int col = wc * 64 + j * 16 + lm;
                    float v = fmaxf(acc[m][j][r] + b_in[col], 0.f);
                    h0_out[(size_t)row * HDIM + col] = (f16)v;
                }
            }
        }
    }
}

// combo + hs0 = dis*h0 (one wave per node)
__global__ __launch_bounds__(256) void combo_scale(
        const int* __restrict__ deg_cnt, const f16* __restrict__ h0,
        float4* __restrict__ combo, f16* __restrict__ hs0) {
    int node = blockIdx.x * 4 + (threadIdx.x >> 6);
    int lane = threadIdx.x & 63;
    if (node >= N_NODES) return;
    float d = (float)(deg_cnt[node] + 1);
    float dis = rsqrtf(d);
    float g = sqrtf(d);
    if (lane == 0) combo[node] = make_float4(dis, 0.8f * dis, (0.8f / d + 0.1f) * g, g);
    f16x2 h = ((const f16x2*)h0)[(size_t)node * 64 + lane];
    f16x2 o; o[0] = (f16)(dis * (float)h[0]); o[1] = (f16)(dis * (float)h[1]);
    ((f16x2*)hs0)[(size_t)node * 64 + lane] = o;
}

// ---------------- aggregation + residual combine (round-10 proven form) ----------------
// One wave per node, zero LDS (full occupancy). Lane owns f16x2 of the 256B row;
// one gather instruction per edge, 8 in flight. hs pre-scaled by dis[r].

__global__ __launch_bounds__(256) void agg_combine(
        const f16* __restrict__ hs, const f16* __restrict__ h0_16,
        const int* __restrict__ col_cnt, const unsigned short* __restrict__ e_slot,
        const float4* __restrict__ combo, f16* __restrict__ p16) {
    int w = (blockIdx.x * blockDim.x + threadIdx.x) >> 6;
    int lane = threadIdx.x & 63;
    if (w >= N_NODES) return;
    int cnt = col_cnt[w]; if (cnt > CAP) cnt = CAP;
    const f16x2* hp = (const f16x2*)hs;                 // row = node*64 + lane
    const unsigned short* slots = e_slot + (size_t)w * CAP;
    float ax = 0.f, ay = 0.f;
    int e = 0;
    for (; e + 8 <= cnt; e += 8) {
        ushort4 sa = *(const ushort4*)(slots + e);      // wave-uniform 8B loads
        ushort4 sb = *(const ushort4*)(slots + e + 4);
        f16x2 v0 = hp[(size_t)sa.x * 64 + lane];
        f16x2 v1 = hp[(size_t)sa.y * 64 + lane];
        f16x2 v2 = hp[(size_t)sa.z * 64 + lane];
        f16x2 v3 = hp[(size_t)sa.w * 64 + lane];
        f16x2 v4 = hp[(size_t)sb.x * 64 + lane];
        f16x2 v5 = hp[(size_t)sb.y * 64 + lane];
        f16x2 v6 = hp[(size_t)sb.z * 64 + lane];
        f16x2 v7 = hp[(size_t)sb.w * 64 + lane];
        ax += (float)v0[0] + (float)v1[0] + (float)v2[0] + (float)v3[0]
            + (float)v4[0] + (float)v5[0] + (float)v6[0] + (float)v7[0];
        ay += (float)v0[1] + (float)v1[1] + (float)v2[1] + (float)v3[1]
            + (float)v4[1] + (float)v5[1] + (float)v6[1] + (float)v7[1];
    }
    for (; e + 4 <= cnt; e += 4) {
        ushort4 s4 = *(const ushort4*)(slots + e);
        f16x2 v0 = hp[(size_t)s4.x * 64 + lane];
        f16x2 v1 = hp[(size_t)s4.y * 64 + lane];
        f16x2 v2 = hp[(size_t)s4.z * 64 + lane];
        f16x2 v3 = hp[(size_t)s4.w * 64 + lane];
        ax += (float)v0[0] + (float)v1[0] + (float)v2[0] + (float)v3[0];
        ay += (float)v0[1] + (float)v1[1] + (float)v2[1] + (float)v3[1];
    }
    for (; e < cnt; ++e) {
        int r = slots[e];
        f16x2 v = hp[(size_t)r * 64 + lane];
        ax += (float)v[0];
        ay += (float)v[1];
    }
    float4 cb = combo[w];
    f16x2 hw = hp[(size_t)w * 64 + lane];
    f16x2 h0v = ((const f16x2*)h0_16)[(size_t)w * 64 + lane];
    float px = cb.y * ax + cb.z * (float)hw[0] + 0.1f * (float)h0v[0];
    float py = cb.y * ay + cb.z * (float)hw[1] + 0.1f * (float)h0v[1];
    f16x2 o; o[0] = (f16)px; o[1] = (f16)py;
    ((f16x2*)p16)[(size_t)w * 64 + lane] = o;
}

// ---------------- fp16 MFMA GEMM (layer): hs_out = dis * max(A@W, sb) ----------------

__global__ __launch_bounds__(256, 2) void gemm_mfma(
        const f16* __restrict__ A, const f16* __restrict__ Wt,
        const float* __restrict__ sb, const float4* __restrict__ combo,
        f16* __restrict__ hs_out) {
    __shared__ uint4 smem4[3072];                // 48 KiB: A 16K | Wt 32K
    char* smem = (char*)smem4;
    int tid = threadIdx.x;
    int r0 = blockIdx.x * 64;

    const uint4* Asrc = (const uint4*)A;
    for (int c = tid; c < 1024; c += 256) {
        int row = c >> 4, q = c & 15;
        int grow = r0 + row; if (grow >= N_NODES) grow = N_NODES - 1;
        uint4 v = Asrc[(size_t)grow * 16 + q];
        *(uint4*)&smem[row * 256 + ((q * 16) ^ ((row & 7) << 4))] = v;
    }
    const uint4* Wsrc = (const uint4*)Wt;
    for (int c = tid; c < 2048; c += 256) {
        int n = c >> 4, q = c & 15;
        uint4 v = Wsrc[n * 16 + q];
        *(uint4*)&smem[WT_OFF + n * 256 + ((q * 16) ^ ((n & 7) << 4))] = v;
    }
    __syncthreads();

    int l = tid & 63, w = tid >> 6;
    int wr = w >> 1, wc = w & 1;
    int lg = l >> 4, lm = l & 15;

    union F8 { f16x8 v8; struct { f16x4 lo, hi; } p; };
    f32x4 acc[2][4];
#pragma unroll
    for (int m = 0; m < 2; ++m)
#pragma unroll
        for (int j = 0; j < 4; ++j) acc[m][j] = (f32x4){0.f, 0.f, 0.f, 0.f};

#pragma unroll
    for (int kk = 0; kk < 4; ++kk) {
        int boff = kk * 64 + lg * 8;
        F8 a[2], bb[4];
#pragma unroll
        for (int m = 0; m < 2; ++m) {
            int row = wr * 32 + m * 16 + lm;
            int swz = (row & 7) << 4;
            int rb = row * 256;
            a[m].p.lo = *(const f16x4*)&smem[rb + (boff ^ swz)];
            a[m].p.hi = *(const f16x4*)&smem[rb + ((boff + 32) ^ swz)];
        }
#pragma unroll
        for (int j = 0; j < 4; ++j) {
            int n = wc * 64 + j * 16 + lm;
            int swz = (n & 7) << 4;
            int nb = WT_OFF + n * 256;
            bb[j].p.lo = *(const f16x4*)&smem[nb + (boff ^ swz)];
            bb[j].p.hi = *(const f16x4*)&smem[nb + ((boff + 32) ^ swz)];
        }
#pragma unroll
        for (int m = 0; m < 2; ++m)
#pragma unroll
            for (int j = 0; j < 4; ++j)
                acc[m][j] = __builtin_amdgcn_mfma_f32_16x16x32_f16(a[m].v8, bb[j].v8, acc[m][j], 0, 0, 0);
    }

#pragma unroll
    for (int m = 0; m < 2; ++m) {
#pragma unroll
        for (int r = 0; r < 4; ++r) {
            int row = r0 + wr * 32 + m * 16 + lg * 4 + r;
            if (row < N_NODES) {
                float dis = combo[row].x;
#pragma unroll
                for (int j = 0; j < 4; ++j) {
                    int col = wc * 64 + j * 16 + lm;
                    float v = fmaxf(acc[m][j][r], sb[col]);
                    hs_out[(size_t)row * HDIM + col] = (f16)(dis * v);
                }
            }
        }
    }
}

// ---------------- output layer via MFMA: out = (hs/dis) @ W_out + b_out ----------------
#define WOT_OFF 16384

__global__ __launch_bounds__(256) void out_mfma(
        const f16* __restrict__ A, const f16* __restrict__ Wot,
        const float* __restrict__ bo, const float4* __restrict__ combo,
        float* __restrict__ out) {
    __shared__ uint4 smem4[1792];                // 28 KiB: A 16K | Wot 12K
    char* smem = (char*)smem4;
    int tid = threadIdx.x;
    int r0 = blockIdx.x * 64;

    const uint4* Asrc = (const uint4*)A;
    for (int c = tid; c < 1024; c += 256) {
        int row = c >> 4, q = c & 15;
        int grow = r0 + row; if (grow >= N_NODES) grow = N_NODES - 1;
        uint4 v = Asrc[(size_t)grow * 16 + q];
        *(uint4*)&smem[row * 256 + ((q * 16) ^ ((row & 7) << 4))] = v;
    }
    const uint4* Wsrc = (const uint4*)Wot;
    for (int c = tid; c < 768; c += 256) {
        int n = c >> 4, q = c & 15;
        uint4 v = Wsrc[n * 16 + q];
        *(uint4*)&smem[WOT_OFF + n * 256 + ((q * 16) ^ ((n & 7) << 4))] = v;
    }
    __syncthreads();

    int l = tid & 63, w = tid >> 6;
    int lg = l >> 4, lm = l & 15;

    union F8 { f16x8 v8; struct { f16x4 lo, hi; } p; };
    f32x4 acc[3];
#pragma unroll
    for (int j = 0; j < 3; ++j) acc[j] = (f32x4){0.f, 0.f, 0.f, 0.f};

#pragma unroll
    for (int kk = 0; kk < 4; ++kk) {
        int boff = kk * 64 + lg * 8;
        F8 a, b[3];
        int row = w * 16 + lm;
        int swz = (row & 7) << 4;
        int rb = row * 256;
        a.p.lo = *(const f16x4*)&smem[rb + (boff ^ swz)];
        a.p.hi = *(const f16x4*)&smem[rb + ((boff + 32) ^ swz)];
#pragma unroll
        for (int j = 0; j < 3; ++j) {
            int n = j * 16 + lm;
            int swz2 = (n & 7) << 4;
            int nb = WOT_OFF + n * 256;
            b[j].p.lo = *(const f16x4*)&smem[nb + (boff ^ swz2)];
            b[j].p.hi = *(const f16x4*)&smem[nb + ((boff + 32) ^ swz2)];
        }
#pragma unroll
        for (int j = 0; j < 3; ++j)
            acc[j] = __builtin_amdgcn_mfma_f32_16x16x32_f16(a.v8, b[j].v8, acc[j], 0, 0, 0);
    }

#pragma unroll
    for (int r = 0; r < 4; ++r) {
        int row = r0 + w * 16 + lg * 4 + r;
        if (row < N_NODES) {
            float g2 = combo[row].w;      // 1/dis: un-scale the hs row
#pragma unroll
            for (int j = 0; j < 3; ++j) {
                int col = j * 16 + lm;
                if (col < N_CLASSES)
                    out[(size_t)row * N_CLASSES + col] = g2 * acc[j][r] + bo[col];
            }
        }
    }
}

// ---------------- launch ----------------

extern "C" void kernel_launch(void* const* d_in, const int* in_sizes, int n_in,
                              void* d_out, int out_size, void* d_ws, size_t ws_size,
                              hipStream_t stream) {
    const float* x       = (const float*)d_in[0];
    const int*   ei      = (const int*)d_in[1];
    const float* W_in    = (const float*)d_in[2];
    const float* b_in    = (const float*)d_in[3];
    const float* gcn_W   = (const float*)d_in[4];
    const float* srelu_b = (const float*)d_in[5];
    const float* W_out   = (const float*)d_in[6];
    const float* b_out   = (const float*)d_in[7];
    float* outp = (float*)d_out;

    char* ws = (char*)d_ws;
    size_t off = 0;
    auto alloc = [&](size_t bytes) -> void* {
        void* p = ws + off;
        off += (bytes + 255) & ~(size_t)255;
        return p;
    };
    int*    deg_cnt = (int*)alloc((size_t)N_NODES * 4);
    int*    col_cnt = (int*)alloc((size_t)N_NODES * 4);
    float4* combo   = (float4*)alloc((size_t)N_NODES * 16);
    unsigned short* e_slot = (unsigned short*)alloc((size_t)N_NODES * CAP * 2);
    f16*    wt16    = (f16*)alloc((size_t)9 * HDIM * HDIM * 2);
    f16*    wot16   = (f16*)alloc((size_t)48 * HDIM * 2);
    f16*    h0_16   = (f16*)alloc((size_t)N_NODES * HDIM * 2);
    f16*    hs0     = (f16*)alloc((size_t)N_NODES * HDIM * 2);
    f16*    hsA     = (f16*)alloc((size_t)N_NODES * HDIM * 2);
    f16*    hsB     = (f16*)alloc((size_t)N_NODES * HDIM * 2);
    f16*    p16     = (f16*)alloc((size_t)N_NODES * HDIM * 2);

    hipMemsetAsync(deg_cnt, 0, (size_t)N_NODES * 4, stream);
    hipMemsetAsync(col_cnt, 0, (size_t)N_NODES * 4, stream);

    setup_kernel<<<BUILD_BLOCKS + GEMM0_BLOCKS + PREP_BLOCKS, 256, 0, stream>>>(
        ei, x, W_in, b_in, gcn_W, W_out, deg_cnt, col_cnt, e_slot, wt16, wot16, h0_16);
    combo_scale<<<(N_NODES + 3) / 4, 256, 0, stream>>>(deg_cnt, h0_16, combo, hs0);

    const f16* hcur = hs0;
    for (int l = 0; l < N_LAYERS; ++l) {
        f16* hnext = (l & 1) ? hsB : hsA;
        agg_combine<<<(N_NODES * 64 + 255) / 256, 256, 0, stream>>>(
            hcur, h0_16, col_cnt, e_slot, combo, p16);
        gemm_mfma<<<(N_NODES + 63) / 64, 256, 0, stream>>>(
            p16, wt16 + (size_t)(l + 1) * HDIM * HDIM,
            srelu_b + (size_t)l * HDIM, combo, hnext);
        hcur = hnext;
    }

    out_mfma<<<(N_NODES + 63) / 64, 256, 0, stream>>>(hcur, wot16, b_out, combo, outp);
}

// Round 13
// 666.225 us; speedup vs baseline: 2.0529x; 1.0364x over previous
//
#include <hip/hip_runtime.h>

#define N_NODES 50000
#define N_EDGES 1600000
#define HDIM 128
#define N_CLASSES 40
#define N_LAYERS 8
#define CAP 128                 // max stored in-degree; Poisson(32): P(>128) ~ 1e-19/node

#define BUILD_BLOCKS 782        // ceil(1.6M/8/256)
#define GEMM0_BLOCKS 782        // ceil(50000/64)
#define PREP_BLOCKS  600        // wt 576 + wot 24
#define WT_OFF 16384            // setup gemm0 LDS: A-tile 16K | Wt 32K

typedef _Float16 f16;
typedef _Float16 f16x2 __attribute__((ext_vector_type(2)));
typedef _Float16 f16x4 __attribute__((ext_vector_type(4)));
typedef _Float16 f16x8 __attribute__((ext_vector_type(8)));
typedef float f32x4 __attribute__((ext_vector_type(4)));
typedef int i32x4 __attribute__((ext_vector_type(4)));

__device__ __forceinline__ int clamp_idx(int v) {
    v = v < 0 ? 0 : v;
    return v >= N_NODES ? N_NODES - 1 : v;
}

// ---------------- fused setup: CSR build || gemm0, INTERLEAVED block roles ----------------

__global__ __launch_bounds__(256) void setup_kernel(
        const int* __restrict__ ei, const float* __restrict__ x,
        const float* __restrict__ W_in, const float* __restrict__ b_in,
        const float* __restrict__ gcn_W, const float* __restrict__ W_out,
        int* __restrict__ deg_cnt, int* __restrict__ col_cnt,
        unsigned short* __restrict__ e_slot,
        f16* __restrict__ wt, f16* __restrict__ wot, f16* __restrict__ h0_out) {
    __shared__ uint4 smem4[3072];                // 48 KiB (gemm0 role only)
    char* smem = (char*)smem4;
    int b = blockIdx.x;
    int tid = threadIdx.x;

    if (b < BUILD_BLOCKS + GEMM0_BLOCKS && (b & 1) == 0) {
        // ---- build role ----
        int t = (b >> 1) * 256 + tid;            // 8 edges per thread
        if (t < N_EDGES / 8) {
            i32x4 ra = ((const i32x4*)ei)[2 * t];
            i32x4 rb = ((const i32x4*)ei)[2 * t + 1];
            i32x4 ca = ((const i32x4*)(ei + N_EDGES))[2 * t];
            i32x4 cb = ((const i32x4*)(ei + N_EDGES))[2 * t + 1];
            int rs[8] = {ra[0], ra[1], ra[2], ra[3], rb[0], rb[1], rb[2], rb[3]};
            int cs[8] = {ca[0], ca[1], ca[2], ca[3], cb[0], cb[1], cb[2], cb[3]};
#pragma unroll
            for (int i = 0; i < 8; ++i) {
                int r = clamp_idx(rs[i]);
                int c = clamp_idx(cs[i]);
                if (r != c) {
                    atomicAdd(&deg_cnt[r], 1);               // fire-and-forget
                    int s = atomicAdd(&col_cnt[c], 1);       // returned: slot
                    if (s < CAP) e_slot[(size_t)c * CAP + s] = (unsigned short)r;
                }
            }
        }
        return;
    }
    if (b >= BUILD_BLOCKS + GEMM0_BLOCKS) {
        // ---- prep role (tail) ----
        int idx = (b - BUILD_BLOCKS - GEMM0_BLOCKS) * 256 + tid;
        if (idx < 9 * HDIM * HDIM) {
            int mat = idx >> 14;
            int rem = idx & 16383;
            int k = rem >> 7, n = rem & 127;
            float v = (mat == 0) ? W_in[rem] : gcn_W[(mat - 1) * 16384 + rem];
            wt[mat * 16384 + n * 128 + k] = (f16)v;
        } else {
            int j = idx - 9 * HDIM * HDIM;                   // 0..6143
            if (j < 48 * 128) {
                int n = j >> 7, k = j & 127;                 // wot[n][k], pad n>=40
                wot[n * 128 + k] = (n < N_CLASSES) ? (f16)W_out[k * N_CLASSES + n] : (f16)0.f;
            }
        }
        return;
    }

    // ---- gemm0 role (odd blocks): h0 = relu(x @ W_in + b_in) ----
    int r0 = (b >> 1) * 64;

    const float4* x4 = (const float4*)x;
    for (int c = tid; c < 2048; c += 256) {
        int row = c >> 5, f4 = c & 31;
        int grow = r0 + row; if (grow >= N_NODES) grow = N_NODES - 1;
        float4 v = x4[(size_t)grow * 32 + f4];
        f16x4 h; h[0] = (f16)v.x; h[1] = (f16)v.y; h[2] = (f16)v.z; h[3] = (f16)v.w;
        int addr = row * 256 + ((((f4 >> 1) << 4) ^ ((row & 7) << 4)) + (f4 & 1) * 8);
        *(f16x4*)&smem[addr] = h;
    }
    for (int idx = tid; idx < 16384; idx += 256) {
        int k = idx >> 7, n = idx & 127;
        float v = W_in[k * 128 + n];
        int addr = WT_OFF + n * 256 + ((((k >> 3) << 4) ^ ((n & 7) << 4)) + (k & 7) * 2);
        *(f16*)&smem[addr] = (f16)v;
    }
    __syncthreads();

    int l = tid & 63, w = tid >> 6;
    int wr = w >> 1, wc = w & 1;
    int lg = l >> 4, lm = l & 15;
    union F8 { f16x8 v8; struct { f16x4 lo, hi; } p; };
    f32x4 acc[2][4];
#pragma unroll
    for (int m = 0; m < 2; ++m)
#pragma unroll
        for (int j = 0; j < 4; ++j) acc[m][j] = (f32x4){0.f, 0.f, 0.f, 0.f};
#pragma unroll
    for (int kk = 0; kk < 4; ++kk) {
        int boff = kk * 64 + lg * 8;
        F8 a[2], bb[4];
#pragma unroll
        for (int m = 0; m < 2; ++m) {
            int row = wr * 32 + m * 16 + lm;
            int swz = (row & 7) << 4;
            int rb = row * 256;
            a[m].p.lo = *(const f16x4*)&smem[rb + (boff ^ swz)];
            a[m].p.hi = *(const f16x4*)&smem[rb + ((boff + 32) ^ swz)];
        }
#pragma unroll
        for (int j = 0; j < 4; ++j) {
            int n = wc * 64 + j * 16 + lm;
            int swz = (n & 7) << 4;
            int nb = WT_OFF + n * 256;
            bb[j].p.lo = *(const f16x4*)&smem[nb + (boff ^ swz)];
            bb[j].p.hi = *(const f16x4*)&smem[nb + ((boff + 32) ^ swz)];
        }
#pragma unroll
        for (int m = 0; m < 2; ++m)
#pragma unroll
            for (int j = 0; j < 4; ++j)
                acc[m][j] = __builtin_amdgcn_mfma_f32_16x16x32_f16(a[m].v8, bb[j].v8, acc[m][j], 0, 0, 0);
    }
#pragma unroll
    for (int m = 0; m < 2; ++m) {
#pragma unroll
        for (int r = 0; r < 4; ++r) {
            int row = r0 + wr * 32 + m * 16 + lg * 4 + r;
            if (row < N_NODES) {
#pragma unroll
                for (int j = 0; j < 4; ++j) {
                    int col = wc * 64 + j * 16 + lm;
                    float v = fmaxf(acc[m][j][r] + b_in[col], 0.f);
                    h0_out[(size_t)row * HDIM + col] = (f16)v;
                }
            }
        }
    }
}

// combo + hs0 = dis*h0 (one wave per node)
__global__ __launch_bounds__(256) void combo_scale(
        const int* __restrict__ deg_cnt, const f16* __restrict__ h0,
        float4* __restrict__ combo, f16* __restrict__ hs0) {
    int node = blockIdx.x * 4 + (threadIdx.x >> 6);
    int lane = threadIdx.x & 63;
    if (node >= N_NODES) return;
    float d = (float)(deg_cnt[node] + 1);
    float dis = rsqrtf(d);
    float g = sqrtf(d);
    if (lane == 0) combo[node] = make_float4(dis, 0.8f * dis, (0.8f / d + 0.1f) * g, g);
    f16x2 h = ((const f16x2*)h0)[(size_t)node * 64 + lane];
    f16x2 o; o[0] = (f16)(dis * (float)h[0]); o[1] = (f16)(dis * (float)h[1]);
    ((f16x2*)hs0)[(size_t)node * 64 + lane] = o;
}

// ---------------- aggregation + residual combine (proven form, untouched) ----------------

__global__ __launch_bounds__(256) void agg_combine(
        const f16* __restrict__ hs, const f16* __restrict__ h0_16,
        const int* __restrict__ col_cnt, const unsigned short* __restrict__ e_slot,
        const float4* __restrict__ combo, f16* __restrict__ p16) {
    int w = (blockIdx.x * blockDim.x + threadIdx.x) >> 6;
    int lane = threadIdx.x & 63;
    if (w >= N_NODES) return;
    int cnt = col_cnt[w]; if (cnt > CAP) cnt = CAP;
    const f16x2* hp = (const f16x2*)hs;                 // row = node*64 + lane
    const unsigned short* slots = e_slot + (size_t)w * CAP;
    float ax = 0.f, ay = 0.f;
    int e = 0;
    for (; e + 8 <= cnt; e += 8) {
        ushort4 sa = *(const ushort4*)(slots + e);      // wave-uniform 8B loads
        ushort4 sb = *(const ushort4*)(slots + e + 4);
        f16x2 v0 = hp[(size_t)sa.x * 64 + lane];
        f16x2 v1 = hp[(size_t)sa.y * 64 + lane];
        f16x2 v2 = hp[(size_t)sa.z * 64 + lane];
        f16x2 v3 = hp[(size_t)sa.w * 64 + lane];
        f16x2 v4 = hp[(size_t)sb.x * 64 + lane];
        f16x2 v5 = hp[(size_t)sb.y * 64 + lane];
        f16x2 v6 = hp[(size_t)sb.z * 64 + lane];
        f16x2 v7 = hp[(size_t)sb.w * 64 + lane];
        ax += (float)v0[0] + (float)v1[0] + (float)v2[0] + (float)v3[0]
            + (float)v4[0] + (float)v5[0] + (float)v6[0] + (float)v7[0];
        ay += (float)v0[1] + (float)v1[1] + (float)v2[1] + (float)v3[1]
            + (float)v4[1] + (float)v5[1] + (float)v6[1] + (float)v7[1];
    }
    for (; e + 4 <= cnt; e += 4) {
        ushort4 s4 = *(const ushort4*)(slots + e);
        f16x2 v0 = hp[(size_t)s4.x * 64 + lane];
        f16x2 v1 = hp[(size_t)s4.y * 64 + lane];
        f16x2 v2 = hp[(size_t)s4.z * 64 + lane];
        f16x2 v3 = hp[(size_t)s4.w * 64 + lane];
        ax += (float)v0[0] + (float)v1[0] + (float)v2[0] + (float)v3[0];
        ay += (float)v0[1] + (float)v1[1] + (float)v2[1] + (float)v3[1];
    }
    for (; e < cnt; ++e) {
        int r = slots[e];
        f16x2 v = hp[(size_t)r * 64 + lane];
        ax += (float)v[0];
        ay += (float)v[1];
    }
    float4 cb = combo[w];
    f16x2 hw = hp[(size_t)w * 64 + lane];
    f16x2 h0v = ((const f16x2*)h0_16)[(size_t)w * 64 + lane];
    float px = cb.y * ax + cb.z * (float)hw[0] + 0.1f * (float)h0v[0];
    float py = cb.y * ay + cb.z * (float)hw[1] + 0.1f * (float)h0v[1];
    f16x2 o; o[0] = (f16)px; o[1] = (f16)py;
    ((f16x2*)p16)[(size_t)w * 64 + lane] = o;
}

// ---------------- fp16 MFMA GEMM (layer), DIRECT-A: hs_out = dis * max(A@W, sb) ----------------
// LDS holds only Wt (32 KiB). A-fragments load straight from global to registers
// (16x16x32 A-layout = 8 contiguous f16/lane -> two coalesced 8B loads), issued
// before the barrier. Wave owns 16 rows x all 128 cols (8 col-tiles).

__global__ __launch_bounds__(256, 4) void gemm_mfma(
        const f16* __restrict__ A, const f16* __restrict__ Wt,
        const float* __restrict__ sb, const float4* __restrict__ combo,
        f16* __restrict__ hs_out) {
    __shared__ uint4 smem4[2048];                // 32 KiB: Wt only
    char* smem = (char*)smem4;
    int tid = threadIdx.x;
    int r0 = blockIdx.x * 64;

    const uint4* Wsrc = (const uint4*)Wt;
    for (int c = tid; c < 2048; c += 256) {
        int n = c >> 4, q = c & 15;
        uint4 v = Wsrc[n * 16 + q];
        *(uint4*)&smem[n * 256 + ((q * 16) ^ ((n & 7) << 4))] = v;
    }

    int lane = tid & 63, w = tid >> 6;
    int lg = lane >> 4, lm = lane & 15;
    int arow = r0 + w * 16 + lm; if (arow >= N_NODES) arow = N_NODES - 1;
    const f16* Ar = A + (size_t)arow * HDIM;
    union F8 { f16x8 v8; struct { f16x4 lo, hi; } p; };
    F8 a[4];
#pragma unroll
    for (int kk = 0; kk < 4; ++kk) {
        a[kk].p.lo = *(const f16x4*)&Ar[kk * 32 + lg * 4];
        a[kk].p.hi = *(const f16x4*)&Ar[kk * 32 + lg * 4 + 16];
    }
    __syncthreads();

    f32x4 acc[8];
#pragma unroll
    for (int j = 0; j < 8; ++j) acc[j] = (f32x4){0.f, 0.f, 0.f, 0.f};
#pragma unroll
    for (int kk = 0; kk < 4; ++kk) {
        int boff = kk * 64 + lg * 8;
#pragma unroll
        for (int j = 0; j < 8; ++j) {
            int n = j * 16 + lm;
            int swz = (n & 7) << 4;
            F8 b;
            b.p.lo = *(const f16x4*)&smem[n * 256 + (boff ^ swz)];
            b.p.hi = *(const f16x4*)&smem[n * 256 + ((boff + 32) ^ swz)];
            acc[j] = __builtin_amdgcn_mfma_f32_16x16x32_f16(a[kk].v8, b.v8, acc[j], 0, 0, 0);
        }
    }
#pragma unroll
    for (int r = 0; r < 4; ++r) {
        int row = r0 + w * 16 + lg * 4 + r;
        if (row < N_NODES) {
            float dis = combo[row].x;
#pragma unroll
            for (int j = 0; j < 8; ++j) {
                int col = j * 16 + lm;
                float v = fmaxf(acc[j][r], sb[col]);
                hs_out[(size_t)row * HDIM + col] = (f16)(dis * v);
            }
        }
    }
}

// ---------------- output layer, DIRECT-A: out = (hs/dis) @ W_out + b_out ----------------

__global__ __launch_bounds__(256, 4) void out_mfma(
        const f16* __restrict__ A, const f16* __restrict__ Wot,
        const float* __restrict__ bo, const float4* __restrict__ combo,
        float* __restrict__ out) {
    __shared__ uint4 smem4[768];                 // 12 KiB: Wot only (48 cols)
    char* smem = (char*)smem4;
    int tid = threadIdx.x;
    int r0 = blockIdx.x * 64;

    const uint4* Wsrc = (const uint4*)Wot;
    for (int c = tid; c < 768; c += 256) {
        int n = c >> 4, q = c & 15;
        uint4 v = Wsrc[n * 16 + q];
        *(uint4*)&smem[n * 256 + ((q * 16) ^ ((n & 7) << 4))] = v;
    }

    int lane = tid & 63, w = tid >> 6;
    int lg = lane >> 4, lm = lane & 15;
    int arow = r0 + w * 16 + lm; if (arow >= N_NODES) arow = N_NODES - 1;
    const f16* Ar = A + (size_t)arow * HDIM;
    union F8 { f16x8 v8; struct { f16x4 lo, hi; } p; };
    F8 a[4];
#pragma unroll
    for (int kk = 0; kk < 4; ++kk) {
        a[kk].p.lo = *(const f16x4*)&Ar[kk * 32 + lg * 4];
        a[kk].p.hi = *(const f16x4*)&Ar[kk * 32 + lg * 4 + 16];
    }
    __syncthreads();

    f32x4 acc[3];
#pragma unroll
    for (int j = 0; j < 3; ++j) acc[j] = (f32x4){0.f, 0.f, 0.f, 0.f};
#pragma unroll
    for (int kk = 0; kk < 4; ++kk) {
        int boff = kk * 64 + lg * 8;
#pragma unroll
        for (int j = 0; j < 3; ++j) {
            int n = j * 16 + lm;
            int swz = (n & 7) << 4;
            F8 b;
            b.p.lo = *(const f16x4*)&smem[n * 256 + (boff ^ swz)];
            b.p.hi = *(const f16x4*)&smem[n * 256 + ((boff + 32) ^ swz)];
            acc[j] = __builtin_amdgcn_mfma_f32_16x16x32_f16(a[kk].v8, b.v8, acc[j], 0, 0, 0);
        }
    }
#pragma unroll
    for (int r = 0; r < 4; ++r) {
        int row = r0 + w * 16 + lg * 4 + r;
        if (row < N_NODES) {
            float g2 = combo[row].w;      // 1/dis: un-scale the hs row
#pragma unroll
            for (int j = 0; j < 3; ++j) {
                int col = j * 16 + lm;
                if (col < N_CLASSES)
                    out[(size_t)row * N_CLASSES + col] = g2 * acc[j][r] + bo[col];
            }
        }
    }
}

// ---------------- launch ----------------

extern "C" void kernel_launch(void* const* d_in, const int* in_sizes, int n_in,
                              void* d_out, int out_size, void* d_ws, size_t ws_size,
                              hipStream_t stream) {
    const float* x       = (const float*)d_in[0];
    const int*   ei      = (const int*)d_in[1];
    const float* W_in    = (const float*)d_in[2];
    const float* b_in    = (const float*)d_in[3];
    const float* gcn_W   = (const float*)d_in[4];
    const float* srelu_b = (const float*)d_in[5];
    const float* W_out   = (const float*)d_in[6];
    const float* b_out   = (const float*)d_in[7];
    float* outp = (float*)d_out;

    char* ws = (char*)d_ws;
    size_t off = 0;
    auto alloc = [&](size_t bytes) -> void* {
        void* p = ws + off;
        off += (bytes + 255) & ~(size_t)255;
        return p;
    };
    int*    deg_cnt = (int*)alloc((size_t)N_NODES * 4);
    int*    col_cnt = (int*)alloc((size_t)N_NODES * 4);
    float4* combo   = (float4*)alloc((size_t)N_NODES * 16);
    unsigned short* e_slot = (unsigned short*)alloc((size_t)N_NODES * CAP * 2);
    f16*    wt16    = (f16*)alloc((size_t)9 * HDIM * HDIM * 2);
    f16*    wot16   = (f16*)alloc((size_t)48 * HDIM * 2);
    f16*    h0_16   = (f16*)alloc((size_t)N_NODES * HDIM * 2);
    f16*    hs0     = (f16*)alloc((size_t)N_NODES * HDIM * 2);
    f16*    hsA     = (f16*)alloc((size_t)N_NODES * HDIM * 2);
    f16*    hsB     = (f16*)alloc((size_t)N_NODES * HDIM * 2);
    f16*    p16     = (f16*)alloc((size_t)N_NODES * HDIM * 2);

    hipMemsetAsync(deg_cnt, 0, (size_t)N_NODES * 4, stream);
    hipMemsetAsync(col_cnt, 0, (size_t)N_NODES * 4, stream);

    setup_kernel<<<BUILD_BLOCKS + GEMM0_BLOCKS + PREP_BLOCKS, 256, 0, stream>>>(
        ei, x, W_in, b_in, gcn_W, W_out, deg_cnt, col_cnt, e_slot, wt16, wot16, h0_16);
    combo_scale<<<(N_NODES + 3) / 4, 256, 0, stream>>>(deg_cnt, h0_16, combo, hs0);

    const f16* hcur = hs0;
    for (int l = 0; l < N_LAYERS; ++l) {
        f16* hnext = (l & 1) ? hsB : hsA;
        agg_combine<<<(N_NODES * 64 + 255) / 256, 256, 0, stream>>>(
            hcur, h0_16, col_cnt, e_slot, combo, p16);
        gemm_mfma<<<(N_NODES + 63) / 64, 256, 0, stream>>>(
            p16, wt16 + (size_t)(l + 1) * HDIM * HDIM,
            srelu_b + (size_t)l * HDIM, combo, hnext);
        hcur = hnext;
    }

    out_mfma<<<(N_NODES + 63) / 64, 256, 0, stream>>>(hcur, wot16, b_out, combo, outp);
}